// Round 1
// baseline (382.152 us; speedup 1.0000x reference)
//
#include <hip/hip_runtime.h>
#include <math.h>

// Problem constants (match reference)
#define TSEQ 32
#define HID  4096
#define NH   32
#define NKVH 8
#define HD   128
#define NCOL 6144           // NH*HD + 2*NKVH*HD = 4096+1024+1024
#define BSZ  16
#define MAXBLK 128
#define CH   256            // attention context chunk

// workspace layout (float offsets)
#define N_PART   (32*32*6144)        // qkv split-K partials (also reused for proj partials)
#define OFF_Q    (N_PART)
#define OFF_KN   (OFF_Q  + 131072)   // 32*8*128
#define OFF_VN   (OFF_KN + 32768)
#define OFF_AT   (OFF_VN + 32768)    // attention output [32][4096]
#define OFF_AP   (OFF_AT + 131072)   // attn partials [32][8][8][520]

// ---------------- kernel 1: QKV split-K GEMM ----------------
// grid (24 col-tiles of 256, 32 k-chunks of 128), block 256
__global__ __launch_bounds__(256) void qkv_kernel(
    const float* __restrict__ hs, const float* __restrict__ Wq,
    const float* __restrict__ Wk, const float* __restrict__ Wv,
    float* __restrict__ part) {
  const int col = blockIdx.x * 256 + threadIdx.x;   // 0..6143
  const int kc  = blockIdx.y;                       // 0..31
  const int k0  = kc * 128;
  const float* W; int ldw, jloc;
  if (col < 4096)      { W = Wq; ldw = 4096; jloc = col; }
  else if (col < 5120) { W = Wk; ldw = 1024; jloc = col - 4096; }
  else                 { W = Wv; ldw = 1024; jloc = col - 5120; }
  float acc[32];
#pragma unroll
  for (int t = 0; t < 32; ++t) acc[t] = 0.f;
  const float* wp = W + (size_t)k0 * ldw + jloc;
#pragma unroll 4
  for (int kk = 0; kk < 128; ++kk) {
    float w = wp[(size_t)kk * ldw];
#pragma unroll
    for (int t = 0; t < 32; ++t)
      acc[t] = fmaf(hs[t * HID + k0 + kk], w, acc[t]);   // hs addr wave-uniform -> s_load
  }
  float* o = part + (size_t)kc * 32 * NCOL + col;
#pragma unroll
  for (int t = 0; t < 32; ++t) o[(size_t)t * NCOL] = acc[t];
}

// ---------------- kernel 2: reduce partials + RoPE + split q/k/v ----------------
// grid (32 rows, 24 col-tiles), block 256
__global__ __launch_bounds__(256) void rope_kernel(
    const float* __restrict__ part, const int* __restrict__ ctxl,
    float* __restrict__ q, float* __restrict__ kn, float* __restrict__ vn) {
  const int t   = blockIdx.x;
  const int col = blockIdx.y * 256 + threadIdx.x;
  float sum = 0.f;
  const float* p = part + (size_t)t * NCOL + col;
#pragma unroll
  for (int c = 0; c < 32; ++c) sum += p[(size_t)c * 32 * NCOL];
  __shared__ float lds[256];
  lds[threadIdx.x] = sum;
  __syncthreads();
  const int d = col & 127;
  float out = sum;
  if (col < 5120) {
    float partner = lds[threadIdx.x ^ 64];
    int   pos = ctxl[t] - 1;
    int   i   = d & 63;
    double inv = exp(-(double)i * (9.210340371976184 / 64.0));  // 10000^(-i/64)
    double f   = (double)pos * inv;
    float c0 = (float)cos(f), s0 = (float)sin(f);
    out = (d < 64) ? (sum * c0 - partner * s0) : (sum * c0 + partner * s0);
  }
  if (col < 4096)      q[(size_t)t * 4096 + col] = out;
  else if (col < 5120) kn[(size_t)t * 1024 + (col - 4096)] = out;
  else                 vn[(size_t)t * 1024 + (col - 5120)] = out;
}

// ---------------- kernel 3: flash-decoding attention partials ----------------
// grid (32 seqs, 8 kv-heads, 8 chunks), block 256 (4 waves)
__global__ __launch_bounds__(256) void attn_kernel(
    const float* __restrict__ kcache, const float* __restrict__ vcache,
    const int* __restrict__ bt, const int* __restrict__ ctxl,
    const float* __restrict__ q, const float* __restrict__ kn,
    const float* __restrict__ vn, float* __restrict__ part) {
  const int t = blockIdx.x, kvh = blockIdx.y, ch = blockIdx.z;
  const int ctx = ctxl[t];
  const int s0 = ch * CH;
  if (s0 >= ctx) return;
  const int ns = min(CH, ctx - s0);
  const int tid = threadIdx.x;
  const int w = tid >> 6, lane = tid & 63;
  const int half = lane >> 5, dl = lane & 31;

  __shared__ float qs[4][128];
  __shared__ int   bts[128];
  __shared__ float sc[4][CH];
  __shared__ float ml[4][2];

  for (int i = tid; i < 512; i += 256)
    qs[i >> 7][i & 127] = q[((size_t)t * NH + kvh * 4 + (i >> 7)) * HD + (i & 127)];
  for (int i = tid; i < 128; i += 256) bts[i] = bt[t * MAXBLK + i];
  __syncthreads();

  // pass 1: scores (half-wave per position)
  for (int i = 0; i < CH / 8; ++i) {
    int sl = i * 8 + w * 2 + half;
    int s  = s0 + sl;
    bool valid = sl < ns;
    float dot0 = 0.f, dot1 = 0.f, dot2 = 0.f, dot3 = 0.f;
    if (valid) {
      const float* kp;
      if (s == ctx - 1) kp = kn + ((size_t)t * NKVH + kvh) * HD;
      else {
        int phys = bts[s >> 4];
        kp = kcache + (((size_t)phys * BSZ + (s & 15)) * NKVH + kvh) * HD;
      }
      float4 k4 = *(const float4*)(kp + dl * 4);
      float4 q0 = *(const float4*)(&qs[0][dl * 4]);
      float4 q1 = *(const float4*)(&qs[1][dl * 4]);
      float4 q2 = *(const float4*)(&qs[2][dl * 4]);
      float4 q3 = *(const float4*)(&qs[3][dl * 4]);
      dot0 = q0.x*k4.x + q0.y*k4.y + q0.z*k4.z + q0.w*k4.w;
      dot1 = q1.x*k4.x + q1.y*k4.y + q1.z*k4.z + q1.w*k4.w;
      dot2 = q2.x*k4.x + q2.y*k4.y + q2.z*k4.z + q2.w*k4.w;
      dot3 = q3.x*k4.x + q3.y*k4.y + q3.z*k4.z + q3.w*k4.w;
    }
#pragma unroll
    for (int m = 1; m < 32; m <<= 1) {
      dot0 += __shfl_xor(dot0, m, 64);
      dot1 += __shfl_xor(dot1, m, 64);
      dot2 += __shfl_xor(dot2, m, 64);
      dot3 += __shfl_xor(dot3, m, 64);
    }
    if (dl == 0) {
      const float scale = 0.08838834764831845f;  // 128^-0.5
      sc[0][sl] = valid ? dot0 * scale : -INFINITY;
      sc[1][sl] = valid ? dot1 * scale : -INFINITY;
      sc[2][sl] = valid ? dot2 * scale : -INFINITY;
      sc[3][sl] = valid ? dot3 * scale : -INFINITY;
    }
  }
  __syncthreads();

  // per-head max + sum, convert scores -> p in LDS (wave w handles head w)
  {
    const int g = w;
    float vals[4];
    float m = -INFINITY;
#pragma unroll
    for (int i = 0; i < 4; ++i) { vals[i] = sc[g][lane + i * 64]; m = fmaxf(m, vals[i]); }
#pragma unroll
    for (int mk = 1; mk < 64; mk <<= 1) m = fmaxf(m, __shfl_xor(m, mk, 64));
    float l = 0.f;
#pragma unroll
    for (int i = 0; i < 4; ++i) {
      float pv = __expf(vals[i] - m);
      sc[g][lane + i * 64] = pv;
      l += pv;
    }
#pragma unroll
    for (int mk = 1; mk < 64; mk <<= 1) l += __shfl_xor(l, mk, 64);
    if (lane == 0) { ml[g][0] = m; ml[g][1] = l; }
  }
  __syncthreads();

  // pass 2: o = sum p*V (wave w = head w, lanes over d)
  {
    const int g = w;
    float ox = 0.f, oy = 0.f;
    for (int sl = 0; sl < ns; ++sl) {
      int s = s0 + sl;
      const float* vp;
      if (s == ctx - 1) vp = vn + ((size_t)t * NKVH + kvh) * HD;
      else {
        int phys = bts[s >> 4];
        vp = vcache + (((size_t)phys * BSZ + (s & 15)) * NKVH + kvh) * HD;
      }
      float2 v2 = *(const float2*)(vp + lane * 2);
      float pv = sc[g][sl];
      ox = fmaf(pv, v2.x, ox);
      oy = fmaf(pv, v2.y, oy);
    }
    float* pp = part + ((size_t)(t * NKVH + kvh) * 8 + ch) * 520;
    if (lane == 0) { pp[g] = ml[g][0]; pp[4 + g] = ml[g][1]; }
    float2 o2; o2.x = ox; o2.y = oy;
    *(float2*)(pp + 8 + g * 128 + lane * 2) = o2;
  }
}

// ---------------- kernel 4: combine chunk partials ----------------
// grid (32, 8), block 128
__global__ __launch_bounds__(128) void combine_kernel(
    const float* __restrict__ part, const int* __restrict__ ctxl,
    float* __restrict__ attn) {
  const int t = blockIdx.x, kvh = blockIdx.y;
  const int nc = (ctxl[t] + CH - 1) / CH;
  const int d = threadIdx.x;
#pragma unroll
  for (int g = 0; g < 4; ++g) {
    float m = -INFINITY;
    for (int c = 0; c < nc; ++c)
      m = fmaxf(m, part[((size_t)(t * NKVH + kvh) * 8 + c) * 520 + g]);
    float l = 0.f, o = 0.f;
    for (int c = 0; c < nc; ++c) {
      const float* pp = part + ((size_t)(t * NKVH + kvh) * 8 + c) * 520;
      float scl = __expf(pp[g] - m);
      l += pp[4 + g] * scl;
      o += pp[8 + g * 128 + d] * scl;
    }
    attn[((size_t)t * NH + kvh * 4 + g) * HD + d] = o / l;
  }
}

// ---------------- kernel 5: output projection split-K GEMM ----------------
// grid (16 col-tiles, 32 k-chunks), block 256
__global__ __launch_bounds__(256) void proj_kernel(
    const float* __restrict__ attn, const float* __restrict__ Wo,
    float* __restrict__ part) {
  const int col = blockIdx.x * 256 + threadIdx.x;  // 0..4095
  const int kc  = blockIdx.y;
  const int k0  = kc * 128;
  float acc[32];
#pragma unroll
  for (int t = 0; t < 32; ++t) acc[t] = 0.f;
  const float* wp = Wo + (size_t)k0 * 4096 + col;
#pragma unroll 4
  for (int kk = 0; kk < 128; ++kk) {
    float w = wp[(size_t)kk * 4096];
#pragma unroll
    for (int t = 0; t < 32; ++t)
      acc[t] = fmaf(attn[t * 4096 + k0 + kk], w, acc[t]);
  }
  float* o = part + (size_t)kc * 32 * 4096 + col;
#pragma unroll
  for (int t = 0; t < 32; ++t) o[(size_t)t * 4096] = acc[t];
}

// ---------------- kernel 6: reduce proj partials -> out ----------------
// grid (32, 16), block 256
__global__ __launch_bounds__(256) void reduce_out(
    const float* __restrict__ part, float* __restrict__ out) {
  const int t = blockIdx.x;
  const int col = blockIdx.y * 256 + threadIdx.x;
  float s = 0.f;
#pragma unroll
  for (int c = 0; c < 32; ++c) s += part[((size_t)c * 32 + t) * 4096 + col];
  out[(size_t)t * 4096 + col] = s;
}

extern "C" void kernel_launch(void* const* d_in, const int* in_sizes, int n_in,
                              void* d_out, int out_size, void* d_ws, size_t ws_size,
                              hipStream_t stream) {
  const float* hs = (const float*)d_in[0];
  const float* Wq = (const float*)d_in[1];
  const float* Wk = (const float*)d_in[2];
  const float* Wv = (const float*)d_in[3];
  const float* Wo = (const float*)d_in[4];
  const float* kc = (const float*)d_in[5];
  const float* vc = (const float*)d_in[6];
  const int*   bt = (const int*)d_in[7];
  const int*   cl = (const int*)d_in[8];
  float* out = (float*)d_out;
  float* ws  = (float*)d_ws;

  float* part = ws;
  float* q    = ws + OFF_Q;
  float* kn   = ws + OFF_KN;
  float* vn   = ws + OFF_VN;
  float* at   = ws + OFF_AT;
  float* ap   = ws + OFF_AP;

  qkv_kernel<<<dim3(24, 32), 256, 0, stream>>>(hs, Wq, Wk, Wv, part);
  rope_kernel<<<dim3(32, 24), 256, 0, stream>>>(part, cl, q, kn, vn);
  attn_kernel<<<dim3(32, 8, 8), 256, 0, stream>>>(kc, vc, bt, cl, q, kn, vn, ap);
  combine_kernel<<<dim3(32, 8), 128, 0, stream>>>(ap, cl, at);
  proj_kernel<<<dim3(16, 32), 256, 0, stream>>>(at, Wo, part);
  reduce_out<<<dim3(32, 16), 256, 0, stream>>>(part, out);
}

// Round 2
// 189.234 us; speedup vs baseline: 2.0195x; 2.0195x over previous
//
#include <hip/hip_runtime.h>
#include <math.h>

// Problem constants (match reference)
#define TSEQ 32
#define HID  4096
#define NH   32
#define NKVH 8
#define HD   128
#define NCOL 6144           // NH*HD + 2*NKVH*HD
#define BSZ  16
#define MAXBLK 128
#define CH   256            // attention context chunk

// workspace layout (float offsets)
#define N_PART   (32*32*6144)        // qkv split-K partials (reused for proj partials)
#define OFF_Q    (N_PART)
#define OFF_KN   (OFF_Q  + 131072)   // 32*32*128
#define OFF_VN   (OFF_KN + 32768)
#define OFF_AT   (OFF_VN + 32768)    // attention output [32][4096]
#define OFF_AP   (OFF_AT + 131072)   // attn partials [32][8][8][520]
#define OFF_TAB  (OFF_AP + 133120)   // rope table [32][64][2]

// ---------------- kernel 0: RoPE cos/sin table ----------------
__global__ __launch_bounds__(256) void rope_table(const int* __restrict__ ctxl,
                                                  float* __restrict__ tab) {
  int idx = blockIdx.x * 256 + threadIdx.x;   // 0..2047
  if (idx >= 32 * 64) return;
  int t = idx >> 6, i = idx & 63;
  double pos = (double)(ctxl[t] - 1);
  double inv = exp(-(double)i * (9.210340371976184 / 64.0));  // 10000^(-i/64)
  double f = pos * inv;
  tab[idx * 2]     = (float)cos(f);
  tab[idx * 2 + 1] = (float)sin(f);
}

// ---------------- kernel 1: QKV split-K GEMM ----------------
// block: 4 waves x (8 rows x 256 cols), float4 W loads; grid (24 col-tiles, 32 k-chunks)
__global__ __launch_bounds__(256) void qkv_kernel(
    const float* __restrict__ hs, const float* __restrict__ Wq,
    const float* __restrict__ Wk, const float* __restrict__ Wv,
    float* __restrict__ part) {
  const int lane = threadIdx.x & 63;
  const int wu = __builtin_amdgcn_readfirstlane(threadIdx.x >> 6);  // wave id, SGPR
  const int col0 = blockIdx.x * 256 + lane * 4;  // 4 consecutive cols per lane
  const int kc = blockIdx.y;
  const int k0 = kc * 128;
  const float* W; int ldw, jloc;
  if (col0 < 4096)      { W = Wq; ldw = 4096; jloc = col0; }
  else if (col0 < 5120) { W = Wk; ldw = 1024; jloc = col0 - 4096; }
  else                  { W = Wv; ldw = 1024; jloc = col0 - 5120; }
  float4 acc[8];
#pragma unroll
  for (int r = 0; r < 8; ++r) acc[r] = make_float4(0.f, 0.f, 0.f, 0.f);
  const float* wp = W + (size_t)k0 * ldw + jloc;
  const float* hp = hs + (size_t)(wu * 8) * HID + k0;   // rows 8w..8w+7, uniform -> s_load
#pragma unroll 4
  for (int kk = 0; kk < 128; ++kk) {
    float4 w4 = *(const float4*)(wp + (size_t)kk * ldw);
#pragma unroll
    for (int r = 0; r < 8; ++r) {
      float h = hp[r * HID + kk];
      acc[r].x = fmaf(h, w4.x, acc[r].x);
      acc[r].y = fmaf(h, w4.y, acc[r].y);
      acc[r].z = fmaf(h, w4.z, acc[r].z);
      acc[r].w = fmaf(h, w4.w, acc[r].w);
    }
  }
  float* o = part + (size_t)kc * 32 * NCOL + (size_t)(wu * 8) * NCOL + blockIdx.x * 256 + lane * 4;
#pragma unroll
  for (int r = 0; r < 8; ++r) *(float4*)(o + (size_t)r * NCOL) = acc[r];
}

// ---------------- kernel 2: reduce partials + RoPE + split q/k/v ----------------
// grid (32 rows, 6 col-tiles of 1024), block 256, float4 per thread
__global__ __launch_bounds__(256) void rope_kernel(
    const float* __restrict__ part, const float* __restrict__ tab,
    float* __restrict__ q, float* __restrict__ kn, float* __restrict__ vn) {
  const int t = blockIdx.x;
  const int col = (blockIdx.y * 256 + threadIdx.x) * 4;
  float4 sum = make_float4(0.f, 0.f, 0.f, 0.f);
  const float* p = part + (size_t)t * NCOL + col;
#pragma unroll
  for (int c = 0; c < 32; ++c) {
    float4 v = *(const float4*)(p + (size_t)c * 32 * NCOL);
    sum.x += v.x; sum.y += v.y; sum.z += v.z; sum.w += v.w;
  }
  __shared__ float lds[1024];
  *(float4*)&lds[threadIdx.x * 4] = sum;
  __syncthreads();
  float out[4] = {sum.x, sum.y, sum.z, sum.w};
  if (col < 5120) {   // uniform per block (1024-col tiles)
#pragma unroll
    for (int j = 0; j < 4; ++j) {
      int d = (col + j) & 127;
      int i = d & 63;
      float partner = lds[(threadIdx.x * 4 + j) ^ 64];
      float c0 = tab[(t * 64 + i) * 2];
      float s0 = tab[(t * 64 + i) * 2 + 1];
      out[j] = (d < 64) ? (out[j] * c0 - partner * s0) : (out[j] * c0 + partner * s0);
    }
  }
  float4 o4 = make_float4(out[0], out[1], out[2], out[3]);
  if (col < 4096)      *(float4*)(q  + (size_t)t * 4096 + col) = o4;
  else if (col < 5120) *(float4*)(kn + (size_t)t * 1024 + (col - 4096)) = o4;
  else                 *(float4*)(vn + (size_t)t * 1024 + (col - 5120)) = o4;
}

// ---------------- kernel 3: flash-decoding attention partials ----------------
// grid (32 seqs, 8 kv-heads, 8 chunks), block 256 (4 waves)
__global__ __launch_bounds__(256) void attn_kernel(
    const float* __restrict__ kcache, const float* __restrict__ vcache,
    const int* __restrict__ bt, const int* __restrict__ ctxl,
    const float* __restrict__ q, const float* __restrict__ kn,
    const float* __restrict__ vn, float* __restrict__ part) {
  const int t = blockIdx.x, kvh = blockIdx.y, ch = blockIdx.z;
  const int ctx = ctxl[t];
  const int s0 = ch * CH;
  if (s0 >= ctx) return;
  const int ns = min(CH, ctx - s0);
  const int tid = threadIdx.x;
  const int w = tid >> 6, lane = tid & 63;
  const int half = lane >> 5, dl = lane & 31;

  __shared__ float qs[4][128];
  __shared__ int   bts[128];
  __shared__ float sc[4][CH];
  __shared__ float ml[4][2];
  __shared__ float op[4][4][128];   // [wave][head][d]

  for (int i = tid; i < 512; i += 256)
    qs[i >> 7][i & 127] = q[((size_t)t * NH + kvh * 4 + (i >> 7)) * HD + (i & 127)];
  for (int i = tid; i < 128; i += 256) bts[i] = bt[t * MAXBLK + i];
  __syncthreads();

  // hoist Q fragment into registers
  float4 q0 = *(const float4*)(&qs[0][dl * 4]);
  float4 q1 = *(const float4*)(&qs[1][dl * 4]);
  float4 q2 = *(const float4*)(&qs[2][dl * 4]);
  float4 q3 = *(const float4*)(&qs[3][dl * 4]);
  const float* knp = kn + ((size_t)t * NKVH + kvh) * HD;
  const float* vnp = vn + ((size_t)t * NKVH + kvh) * HD;

  // pass 1: scores (half-wave per position, 8 positions per block-iter)
#pragma unroll 2
  for (int i = 0; i < CH / 8; ++i) {
    int sl = i * 8 + w * 2 + half;
    bool valid = sl < ns;
    float dot0 = 0.f, dot1 = 0.f, dot2 = 0.f, dot3 = 0.f;
    if (valid) {
      int s = s0 + sl;
      const float* kp;
      if (s == ctx - 1) kp = knp;
      else {
        int phys = bts[s >> 4];
        kp = kcache + (((size_t)phys * BSZ + (s & 15)) * NKVH + kvh) * HD;
      }
      float4 k4 = *(const float4*)(kp + dl * 4);
      dot0 = q0.x*k4.x + q0.y*k4.y + q0.z*k4.z + q0.w*k4.w;
      dot1 = q1.x*k4.x + q1.y*k4.y + q1.z*k4.z + q1.w*k4.w;
      dot2 = q2.x*k4.x + q2.y*k4.y + q2.z*k4.z + q2.w*k4.w;
      dot3 = q3.x*k4.x + q3.y*k4.y + q3.z*k4.z + q3.w*k4.w;
    }
#pragma unroll
    for (int m = 1; m < 32; m <<= 1) {
      dot0 += __shfl_xor(dot0, m, 64);
      dot1 += __shfl_xor(dot1, m, 64);
      dot2 += __shfl_xor(dot2, m, 64);
      dot3 += __shfl_xor(dot3, m, 64);
    }
    if (dl == 0) {
      const float scale = 0.08838834764831845f;
      sc[0][sl] = valid ? dot0 * scale : -INFINITY;
      sc[1][sl] = valid ? dot1 * scale : -INFINITY;
      sc[2][sl] = valid ? dot2 * scale : -INFINITY;
      sc[3][sl] = valid ? dot3 * scale : -INFINITY;
    }
  }
  __syncthreads();

  // per-head max + sum, convert scores -> p in LDS (wave w handles head w)
  {
    const int g = w;
    float vals[4];
    float m = -INFINITY;
#pragma unroll
    for (int i = 0; i < 4; ++i) { vals[i] = sc[g][lane + i * 64]; m = fmaxf(m, vals[i]); }
#pragma unroll
    for (int mk = 1; mk < 64; mk <<= 1) m = fmaxf(m, __shfl_xor(m, mk, 64));
    float l = 0.f;
#pragma unroll
    for (int i = 0; i < 4; ++i) {
      float pv = __expf(vals[i] - m);
      sc[g][lane + i * 64] = pv;
      l += pv;
    }
#pragma unroll
    for (int mk = 1; mk < 64; mk <<= 1) l += __shfl_xor(l, mk, 64);
    if (lane == 0) { ml[g][0] = m; ml[g][1] = l; }
  }
  __syncthreads();

  // pass 2: waves split positions; half-wave x float4 V loads; acc[head][4]
  {
    float acc[4][4];
#pragma unroll
    for (int g = 0; g < 4; ++g)
#pragma unroll
      for (int j = 0; j < 4; ++j) acc[g][j] = 0.f;
    const int base = w * 64;
#pragma unroll 2
    for (int i = 0; i < 32; ++i) {
      int sl = base + i * 2 + half;
      if (sl < ns) {
        int s = s0 + sl;
        const float* vp;
        if (s == ctx - 1) vp = vnp;
        else {
          int phys = bts[s >> 4];
          vp = vcache + (((size_t)phys * BSZ + (s & 15)) * NKVH + kvh) * HD;
        }
        float4 v4 = *(const float4*)(vp + dl * 4);
        float p0 = sc[0][sl], p1 = sc[1][sl], p2 = sc[2][sl], p3 = sc[3][sl];
        acc[0][0] = fmaf(p0, v4.x, acc[0][0]); acc[0][1] = fmaf(p0, v4.y, acc[0][1]);
        acc[0][2] = fmaf(p0, v4.z, acc[0][2]); acc[0][3] = fmaf(p0, v4.w, acc[0][3]);
        acc[1][0] = fmaf(p1, v4.x, acc[1][0]); acc[1][1] = fmaf(p1, v4.y, acc[1][1]);
        acc[1][2] = fmaf(p1, v4.z, acc[1][2]); acc[1][3] = fmaf(p1, v4.w, acc[1][3]);
        acc[2][0] = fmaf(p2, v4.x, acc[2][0]); acc[2][1] = fmaf(p2, v4.y, acc[2][1]);
        acc[2][2] = fmaf(p2, v4.z, acc[2][2]); acc[2][3] = fmaf(p2, v4.w, acc[2][3]);
        acc[3][0] = fmaf(p3, v4.x, acc[3][0]); acc[3][1] = fmaf(p3, v4.y, acc[3][1]);
        acc[3][2] = fmaf(p3, v4.z, acc[3][2]); acc[3][3] = fmaf(p3, v4.w, acc[3][3]);
      }
    }
    // combine halves
#pragma unroll
    for (int g = 0; g < 4; ++g)
#pragma unroll
      for (int j = 0; j < 4; ++j) acc[g][j] += __shfl_xor(acc[g][j], 32, 64);
    if (half == 0) {
#pragma unroll
      for (int g = 0; g < 4; ++g)
        *(float4*)&op[w][g][dl * 4] = make_float4(acc[g][0], acc[g][1], acc[g][2], acc[g][3]);
    }
  }
  __syncthreads();

  // final: reduce 4 wave partials, write chunk partial
  float* pp = part + ((size_t)(t * NKVH + kvh) * 8 + ch) * 520;
  for (int j = tid; j < 512; j += 256) {
    int g = j >> 7, d = j & 127;
    pp[8 + g * 128 + d] = op[0][g][d] + op[1][g][d] + op[2][g][d] + op[3][g][d];
  }
  if (tid < 4) { pp[tid] = ml[tid][0]; pp[4 + tid] = ml[tid][1]; }
}

// ---------------- kernel 4: combine chunk partials ----------------
// grid (32, 8), block 128
__global__ __launch_bounds__(128) void combine_kernel(
    const float* __restrict__ part, const int* __restrict__ ctxl,
    float* __restrict__ attn) {
  const int t = blockIdx.x, kvh = blockIdx.y;
  const int nc = (ctxl[t] + CH - 1) / CH;
  const int d = threadIdx.x;
#pragma unroll
  for (int g = 0; g < 4; ++g) {
    float m = -INFINITY;
    for (int c = 0; c < nc; ++c)
      m = fmaxf(m, part[((size_t)(t * NKVH + kvh) * 8 + c) * 520 + g]);
    float l = 0.f, o = 0.f;
    for (int c = 0; c < nc; ++c) {
      const float* pp = part + ((size_t)(t * NKVH + kvh) * 8 + c) * 520;
      float scl = __expf(pp[g] - m);
      l += pp[4 + g] * scl;
      o += pp[8 + g * 128 + d] * scl;
    }
    attn[((size_t)t * NH + kvh * 4 + g) * HD + d] = o / l;
  }
}

// ---------------- kernel 5: output projection split-K GEMM ----------------
// same structure as qkv: 4 waves x (8 rows x 256 cols); grid (16, 32)
__global__ __launch_bounds__(256) void proj_kernel(
    const float* __restrict__ attn, const float* __restrict__ Wo,
    float* __restrict__ part) {
  const int lane = threadIdx.x & 63;
  const int wu = __builtin_amdgcn_readfirstlane(threadIdx.x >> 6);
  const int col0 = blockIdx.x * 256 + lane * 4;
  const int kc = blockIdx.y;
  const int k0 = kc * 128;
  float4 acc[8];
#pragma unroll
  for (int r = 0; r < 8; ++r) acc[r] = make_float4(0.f, 0.f, 0.f, 0.f);
  const float* wp = Wo + (size_t)k0 * 4096 + col0;
  const float* hp = attn + (size_t)(wu * 8) * 4096 + k0;
#pragma unroll 4
  for (int kk = 0; kk < 128; ++kk) {
    float4 w4 = *(const float4*)(wp + (size_t)kk * 4096);
#pragma unroll
    for (int r = 0; r < 8; ++r) {
      float h = hp[r * 4096 + kk];
      acc[r].x = fmaf(h, w4.x, acc[r].x);
      acc[r].y = fmaf(h, w4.y, acc[r].y);
      acc[r].z = fmaf(h, w4.z, acc[r].z);
      acc[r].w = fmaf(h, w4.w, acc[r].w);
    }
  }
  float* o = part + (size_t)kc * 32 * 4096 + (size_t)(wu * 8) * 4096 + blockIdx.x * 256 + lane * 4;
#pragma unroll
  for (int r = 0; r < 8; ++r) *(float4*)(o + (size_t)r * 4096) = acc[r];
}

// ---------------- kernel 6: reduce proj partials -> out ----------------
// grid (32, 4), block 256, float4 per thread
__global__ __launch_bounds__(256) void reduce_out(
    const float* __restrict__ part, float* __restrict__ out) {
  const int t = blockIdx.x;
  const int col = (blockIdx.y * 256 + threadIdx.x) * 4;
  float4 s0 = make_float4(0.f,0.f,0.f,0.f), s1 = make_float4(0.f,0.f,0.f,0.f);
  const float* p = part + (size_t)t * 4096 + col;
#pragma unroll
  for (int c = 0; c < 32; c += 2) {
    float4 a = *(const float4*)(p + (size_t)c * 32 * 4096);
    float4 b = *(const float4*)(p + (size_t)(c + 1) * 32 * 4096);
    s0.x += a.x; s0.y += a.y; s0.z += a.z; s0.w += a.w;
    s1.x += b.x; s1.y += b.y; s1.z += b.z; s1.w += b.w;
  }
  float4 s = make_float4(s0.x + s1.x, s0.y + s1.y, s0.z + s1.z, s0.w + s1.w);
  *(float4*)(out + (size_t)t * 4096 + col) = s;
}

extern "C" void kernel_launch(void* const* d_in, const int* in_sizes, int n_in,
                              void* d_out, int out_size, void* d_ws, size_t ws_size,
                              hipStream_t stream) {
  const float* hs = (const float*)d_in[0];
  const float* Wq = (const float*)d_in[1];
  const float* Wk = (const float*)d_in[2];
  const float* Wv = (const float*)d_in[3];
  const float* Wo = (const float*)d_in[4];
  const float* kc = (const float*)d_in[5];
  const float* vc = (const float*)d_in[6];
  const int*   bt = (const int*)d_in[7];
  const int*   cl = (const int*)d_in[8];
  float* out = (float*)d_out;
  float* ws  = (float*)d_ws;

  float* part = ws;
  float* q    = ws + OFF_Q;
  float* kn   = ws + OFF_KN;
  float* vn   = ws + OFF_VN;
  float* at   = ws + OFF_AT;
  float* ap   = ws + OFF_AP;
  float* tab  = ws + OFF_TAB;

  rope_table<<<dim3(8), 256, 0, stream>>>(cl, tab);
  qkv_kernel<<<dim3(24, 32), 256, 0, stream>>>(hs, Wq, Wk, Wv, part);
  rope_kernel<<<dim3(32, 6), 256, 0, stream>>>(part, tab, q, kn, vn);
  attn_kernel<<<dim3(32, 8, 8), 256, 0, stream>>>(kc, vc, bt, cl, q, kn, vn, ap);
  combine_kernel<<<dim3(32, 8), 128, 0, stream>>>(ap, cl, at);
  proj_kernel<<<dim3(16, 32), 256, 0, stream>>>(at, Wo, part);
  reduce_out<<<dim3(32, 4), 256, 0, stream>>>(part, out);
}